// Round 2
// 1158.156 us; speedup vs baseline: 1.2253x; 1.2253x over previous
//
#include <hip/hip_runtime.h>
#include <hip/hip_bf16.h>
#include <math.h>

#define D_  1024
#define B_  32
#define T_  2048
#define L_  8
#define P_  720
#define E_  16
#define BP_ (B_*P_)   /* 23040 */

// ---- workspace layout (float offsets) ----
#define OFF_STEPB   ((size_t)0)        // [720][1024]
#define OFF_CKWT    ((size_t)737280)   // ctx_k_w^T  [1024][1024]
#define OFF_SQWT    ((size_t)1785856)  // step_q_w^T [1024][1024]
#define OFF_ATTW    ((size_t)3358720)  // [B][P][8] attn2 weights
#define OFF_LOGITP  ((size_t)3543040)  // [4][B*P][16] logit partials
// ---- memset (atomic-accumulate) region starts here ----
#define OFF_Q1      ((size_t)5017600)  // [8][1024]
#define OFF_Q1P     ((size_t)5025792)  // [8][1024]
#define OFF_NUM     ((size_t)5033984)  // [B][L][1024] softmax numerator
#define OFF_TMP1    ((size_t)5296128)  // [256][1024]
#define OFF_LATCTX  ((size_t)5558272)
#define OFF_K2      ((size_t)5820416)
#define OFF_V2      ((size_t)6082560)
#define OFF_K2P     ((size_t)6344704)
#define OFF_V2A     ((size_t)6606848)
#define OFF_V2P     ((size_t)6868992)
#define OFF_SB1     ((size_t)7131136)  // [720][1024]
#define OFF_DEN     ((size_t)7868416)  // [256] raw softmax denominators (atomic)
// ---- memset region ends here ----
#define WS_FLOATS   ((size_t)7868672)  // ~31.5 MB

__device__ __forceinline__ float gelu_exact(float x){
    return 0.5f * x * (1.0f + erff(x * 0.70710678118654752f));
}

// step_base[p][d] = query_pos[p][d] + pred_len_table[720][d]
__global__ void k_stepb(const float* __restrict__ qpos, const float* __restrict__ plt,
                        float* __restrict__ stepb){
    int p = blockIdx.x;
    int d = threadIdx.x * 4;
    float4 a = *(const float4*)(qpos + (size_t)p*D_ + d);
    float4 b = *(const float4*)(plt  + (size_t)P_*D_ + d);
    a.x += b.x; a.y += b.y; a.z += b.z; a.w += b.w;
    *(float4*)(stepb + (size_t)p*D_ + d) = a;
}

// transpose two 1024x1024 weights (z selects which)
__global__ void k_transpose(const float* __restrict__ s0, const float* __restrict__ s1,
                            float* __restrict__ d0, float* __restrict__ d1){
    __shared__ float tile[32][33];
    const float* src = blockIdx.z ? s1 : s0;
    float*       dst = blockIdx.z ? d1 : d0;
    int tx = threadIdx.x & 31, ty = threadIdx.x >> 5;
    int bx = blockIdx.x * 32, by = blockIdx.y * 32;
    #pragma unroll
    for (int r = 0; r < 4; r++)
        tile[ty + 8*r][tx] = src[(size_t)(by + ty + 8*r)*D_ + bx + tx];
    __syncthreads();
    #pragma unroll
    for (int r = 0; r < 4; r++)
        dst[(size_t)(bx + ty + 8*r)*D_ + by + tx] = tile[tx][ty + 8*r];
}

// C[M,1024] (+)= A[M,1024(chunk)] @ B[1024(chunk),1024] (/rowdiv); split-K via gridDim.z,
// atomic epilogue. MR=8 rows/thread: 2x the blocks of the old 16-row version at the SAME
// atomic count (atomics = M*N*Z) -> 2 waves/SIMD instead of 1 for M=256 launches.
template<int MR>
__global__ void k_gemmT(const float* __restrict__ A, const float* __restrict__ B,
                        float* __restrict__ C, int M, const float* __restrict__ rowdiv){
    int n  = blockIdx.y * 256 + threadIdx.x;
    int kc = D_ / gridDim.z;
    int k0 = blockIdx.z * kc;
    int mb = blockIdx.x * MR;
    float acc[MR];
    #pragma unroll
    for (int m = 0; m < MR; m++) acc[m] = 0.f;
    for (int k = k0; k < k0 + kc; k += 4){
        float b0 = B[(size_t)(k+0)*D_ + n];
        float b1 = B[(size_t)(k+1)*D_ + n];
        float b2 = B[(size_t)(k+2)*D_ + n];
        float b3 = B[(size_t)(k+3)*D_ + n];
        #pragma unroll
        for (int m = 0; m < MR; m++){
            int row = mb + m; if (row > M - 1) row = M - 1;   // uniform clamp
            const float4 av = *(const float4*)(A + (size_t)row*D_ + k);
            acc[m] += av.x*b0 + av.y*b1 + av.z*b2 + av.w*b3;
        }
    }
    #pragma unroll
    for (int m = 0; m < MR; m++){
        int row = mb + m;
        if (row < M){
            float v = acc[m];
            if (rowdiv) v /= rowdiv[row];
            atomicAdd(C + (size_t)row*D_ + n, v);
        }
    }
}

// two independent GEMMs in one launch (blockIdx.z LSB selects), MR=8.
__global__ void k_gemm_pair(const float* __restrict__ A0, const float* __restrict__ B0, float* __restrict__ C0,
                            const float* __restrict__ A1, const float* __restrict__ B1, float* __restrict__ C1,
                            int M){
    const int which = blockIdx.z & 1;
    const float* A  = which ? A1 : A0;
    const float* Bm = which ? B1 : B0;
    float*       C  = which ? C1 : C0;
    int zn = gridDim.z >> 1;
    int z  = blockIdx.z >> 1;
    int n  = blockIdx.y * 256 + threadIdx.x;
    int kc = D_ / zn;
    int k0 = z * kc;
    int mb = blockIdx.x * 8;
    float acc[8];
    #pragma unroll
    for (int m = 0; m < 8; m++) acc[m] = 0.f;
    for (int k = k0; k < k0 + kc; k += 4){
        float b0 = Bm[(size_t)(k+0)*D_ + n];
        float b1 = Bm[(size_t)(k+1)*D_ + n];
        float b2 = Bm[(size_t)(k+2)*D_ + n];
        float b3 = Bm[(size_t)(k+3)*D_ + n];
        #pragma unroll
        for (int m = 0; m < 8; m++){
            int row = mb + m; if (row > M - 1) row = M - 1;
            const float4 av = *(const float4*)(A + (size_t)row*D_ + k);
            acc[m] += av.x*b0 + av.y*b1 + av.z*b2 + av.w*b3;
        }
    }
    #pragma unroll
    for (int m = 0; m < 8; m++){
        int row = mb + m;
        if (row < M){
            atomicAdd(C + (size_t)row*D_ + n, acc[m]);
        }
    }
}

// Fused stage-1 attention: one pass over ctx (268 MB once, not twice).
// Per block: b = blockIdx.x, 128 t-rows in 8 sub-chunks of 16.
// Phase A: stage 16x1024 ctx tile in LDS (padded row 1028 -> spread banks).
// Phase B: thread (t,l,h) half-dots vs q1p, shfl-combine, e=exp(s/32) -> ev[t][l],
//          den partial kept in-register. (no-max softmax is exact: |S| << 1)
// Phase C: threads over d accumulate num[l][d] += e[t][l]*c[t][d] in registers.
// Epilogue: atomic num (16 blocks/b contend) + block-reduced atomic den.
__global__ __launch_bounds__(256) void k_stage1(const float* __restrict__ ctx,
                                                const float* __restrict__ q1p,
                                                float* __restrict__ num,
                                                float* __restrict__ den){
    __shared__ float tile[16][1028];   // 65792 B
    __shared__ float ev[16][8];        // 512 B  -> 2 blocks/CU (132.6 KB of 160)
    const int b   = blockIdx.x;
    const int tid = threadIdx.x;
    const int tt  = tid >> 4;          // 0..15
    const int ll  = (tid >> 1) & 7;    // 0..7
    const int hh  = tid & 1;           // half selector
    float4 acc[8];
    #pragma unroll
    for (int l = 0; l < 8; l++) acc[l] = make_float4(0.f,0.f,0.f,0.f);
    float denacc = 0.f;
    const float4* qp = (const float4*)(q1p + (size_t)ll*D_ + hh*512);
    for (int i = 0; i < 8; i++){
        const int t0 = blockIdx.y*128 + i*16;
        // --- Phase A: coalesced stage ---
        #pragma unroll
        for (int j = 0; j < 16; j++){
            int li = j*256 + tid;
            int t = li >> 8, d4 = li & 255;
            float4 c = *(const float4*)(ctx + ((size_t)(b*T_ + t0 + t))*D_ + 4*d4);
            *(float4*)&tile[t][4*d4] = c;
        }
        __syncthreads();
        // --- Phase B: dots + exp ---
        {
            const float4* cp = (const float4*)&tile[tt][hh*512];
            float4 sa = make_float4(0.f,0.f,0.f,0.f);
            #pragma unroll 4
            for (int d4 = 0; d4 < 128; d4++){
                float4 c = cp[d4];
                float4 q = qp[d4];
                sa.x += c.x*q.x; sa.y += c.y*q.y;
                sa.z += c.z*q.z; sa.w += c.w*q.w;
            }
            float s = (sa.x + sa.y) + (sa.z + sa.w);
            s += __shfl_xor(s, 1);
            if (hh == 0){
                float e = __expf(s * 0.03125f);
                ev[tt][ll] = e;
                denacc += e;
            }
        }
        __syncthreads();
        // --- Phase C: num accumulation (d = tid*4) ---
        #pragma unroll
        for (int t = 0; t < 16; t++){
            float4 c  = *(const float4*)&tile[t][4*tid];
            float4 e0 = *(const float4*)&ev[t][0];
            float4 e1 = *(const float4*)&ev[t][4];
            float ee[8] = {e0.x,e0.y,e0.z,e0.w,e1.x,e1.y,e1.z,e1.w};
            #pragma unroll
            for (int l = 0; l < 8; l++){
                acc[l].x += ee[l]*c.x; acc[l].y += ee[l]*c.y;
                acc[l].z += ee[l]*c.z; acc[l].w += ee[l]*c.w;
            }
        }
        __syncthreads();
    }
    // --- epilogue: num ---
    #pragma unroll
    for (int l = 0; l < 8; l++){
        float* np_ = num + ((size_t)(b*8 + l))*D_ + 4*tid;
        atomicAdd(np_+0, acc[l].x); atomicAdd(np_+1, acc[l].y);
        atomicAdd(np_+2, acc[l].z); atomicAdd(np_+3, acc[l].w);
    }
    // --- epilogue: den (block-reduce then one atomic per (b,l)) ---
    __syncthreads();
    if (hh == 0) ev[tt][ll] = denacc;
    __syncthreads();
    if (tid < 8){
        float s = 0.f;
        #pragma unroll
        for (int t = 0; t < 16; t++) s += ev[t][tid];
        atomicAdd(den + b*8 + tid, s);
    }
}

// attn2 logits + softmax over L=8, thread-per-p:  attw[b][p][l]
__global__ void k_f1(const float* __restrict__ stepb, const float* __restrict__ k2p,
                     float* __restrict__ attw){
    int b = blockIdx.y;
    int p = blockIdx.x * 64 + threadIdx.x;
    if (p >= P_) return;
    const float4* sp = (const float4*)(stepb + (size_t)p * D_);
    const float* kp = k2p + (size_t)b * 8 * D_;
    float acc[8] = {0,0,0,0,0,0,0,0};
    #pragma unroll 2
    for (int d4 = 0; d4 < 256; d4++){
        float4 s = sp[d4];
        #pragma unroll
        for (int l = 0; l < 8; l++){
            const float4 kv = *(const float4*)(kp + (size_t)l*D_ + 4*d4);  // uniform -> s_load
            acc[l] += s.x*kv.x + s.y*kv.y + s.z*kv.z + s.w*kv.w;
        }
    }
    float s8[8];
    #pragma unroll
    for (int l = 0; l < 8; l++) s8[l] = acc[l] * 0.03125f;
    float m = s8[0];
    #pragma unroll
    for (int l = 1; l < 8; l++) m = fmaxf(m, s8[l]);
    float e8[8]; float sum = 0.f;
    #pragma unroll
    for (int l = 0; l < 8; l++){ e8[l] = __expf(s8[l] - m); sum += e8[l]; }
    float inv = 1.0f / sum;
    float4 o0 = make_float4(e8[0]*inv, e8[1]*inv, e8[2]*inv, e8[3]*inv);
    float4 o1 = make_float4(e8[4]*inv, e8[5]*inv, e8[6]*inv, e8[7]*inv);
    size_t bp = (size_t)b * P_ + p;
    *(float4*)(attw + bp*8)     = o0;
    *(float4*)(attw + bp*8 + 4) = o1;
}

// pre->gelu->logit partials over a d-quarter. Thread-per-p; weights via uniform s_loads.
__global__ void k_f2(const float* __restrict__ SB1, const float* __restrict__ v2p,
                     const float* __restrict__ attw, const float* __restrict__ b1,
                     const float* __restrict__ w2, float* __restrict__ logitp){
    int b  = blockIdx.x;
    int p  = blockIdx.y * 64 + threadIdx.x;
    int dq = blockIdx.z;
    if (p >= P_) return;
    size_t bp = (size_t)b * P_ + p;
    float a[8];
    {
        float4 a0 = *(const float4*)(attw + bp*8);
        float4 a1 = *(const float4*)(attw + bp*8 + 4);
        a[0]=a0.x; a[1]=a0.y; a[2]=a0.z; a[3]=a0.w;
        a[4]=a1.x; a[5]=a1.y; a[6]=a1.z; a[7]=a1.w;
    }
    float acc16[16];
    #pragma unroll
    for (int e = 0; e < 16; e++) acc16[e] = 0.f;
    const float* sbp = SB1 + (size_t)p * D_;
    int dbase = dq * 256;
    for (int dd = 0; dd < 256; dd += 4){
        int d = dbase + dd;
        float4 pre = *(const float4*)(sbp + d);
        float4 bb  = *(const float4*)(b1 + d);               // uniform
        pre.x += bb.x; pre.y += bb.y; pre.z += bb.z; pre.w += bb.w;
        #pragma unroll
        for (int l = 0; l < 8; l++){
            const float4 vv = *(const float4*)(v2p + ((size_t)(b*8 + l))*D_ + d);  // uniform
            pre.x += a[l]*vv.x; pre.y += a[l]*vv.y; pre.z += a[l]*vv.z; pre.w += a[l]*vv.w;
        }
        float h[4];
        h[0] = gelu_exact(pre.x); h[1] = gelu_exact(pre.y);
        h[2] = gelu_exact(pre.z); h[3] = gelu_exact(pre.w);
        #pragma unroll
        for (int i = 0; i < 4; i++){
            const float* w2r = w2 + (size_t)(d + i) * E_;    // uniform
            #pragma unroll
            for (int e = 0; e < 16; e++) acc16[e] += h[i] * w2r[e];
        }
    }
    float* outp = logitp + ((size_t)dq * BP_ + bp) * 16;
    #pragma unroll
    for (int e = 0; e < 16; e += 4){
        float4 v = make_float4(acc16[e], acc16[e+1], acc16[e+2], acc16[e+3]);
        *(float4*)(outp + e) = v;
    }
}

// top-2 + masked softmax + expert combine
__global__ void k_f3(const float* __restrict__ logitp, const float* __restrict__ b2,
                     const float* __restrict__ qe, float* __restrict__ out){
    int p = blockIdx.x, b = blockIdx.y;
    size_t bp = (size_t)b * P_ + p;
    float lg[16];
    #pragma unroll
    for (int e = 0; e < 16; e++){
        lg[e] = logitp[((size_t)0*BP_ + bp)*16 + e]
              + logitp[((size_t)1*BP_ + bp)*16 + e]
              + logitp[((size_t)2*BP_ + bp)*16 + e]
              + logitp[((size_t)3*BP_ + bp)*16 + e]
              + b2[e];
    }
    int e1 = 0; float l1 = lg[0];
    #pragma unroll
    for (int e = 1; e < 16; e++) if (lg[e] > l1){ l1 = lg[e]; e1 = e; }   // ties -> lowest idx
    int e2 = 0; float l2 = -1e30f;
    #pragma unroll
    for (int e = 0; e < 16; e++) if (e != e1 && lg[e] > l2){ l2 = lg[e]; e2 = e; }
    float q  = __expf(l2 - l1);
    float w1 = 1.0f / (1.0f + q);
    float w2 = q / (1.0f + q);
    int d = threadIdx.x * 4;
    float4 x1 = *(const float4*)(qe + ((size_t)e1 * P_ + p)*D_ + d);
    float4 x2 = *(const float4*)(qe + ((size_t)e2 * P_ + p)*D_ + d);
    float4 o;
    o.x = w1*x1.x + w2*x2.x; o.y = w1*x1.y + w2*x2.y;
    o.z = w1*x1.z + w2*x2.z; o.w = w1*x1.w + w2*x2.w;
    *(float4*)(out + bp*D_ + d) = o;
}

extern "C" void kernel_launch(void* const* d_in, const int* in_sizes, int n_in,
                              void* d_out, int out_size, void* d_ws, size_t ws_size,
                              hipStream_t stream) {
    (void)in_sizes; (void)n_in; (void)out_size; (void)ws_size;
    const float* ctx  = (const float*)d_in[0];
    const float* qexp = (const float*)d_in[1];
    const float* qpos = (const float*)d_in[2];
    const float* plt  = (const float*)d_in[3];
    const float* lats = (const float*)d_in[4];
    const float* w_lq = (const float*)d_in[5];
    const float* w_ck = (const float*)d_in[6];
    const float* w_cv = (const float*)d_in[7];
    const float* w_lo = (const float*)d_in[8];
    const float* w_sq = (const float*)d_in[9];
    const float* w_lk = (const float*)d_in[10];
    const float* w_lv = (const float*)d_in[11];
    const float* w_so = (const float*)d_in[12];
    const float* w_g1 = (const float*)d_in[13];
    const float* b_g1 = (const float*)d_in[14];
    const float* w_g2 = (const float*)d_in[15];
    const float* b_g2 = (const float*)d_in[16];
    float* out = (float*)d_out;
    float* ws  = (float*)d_ws;

    float* stepb  = ws + OFF_STEPB;
    float* ckwT   = ws + OFF_CKWT;
    float* sqwT   = ws + OFF_SQWT;
    float* attw   = ws + OFF_ATTW;
    float* logitp = ws + OFF_LOGITP;
    float* q1     = ws + OFF_Q1;
    float* q1p    = ws + OFF_Q1P;
    float* num    = ws + OFF_NUM;
    float* tmp1   = ws + OFF_TMP1;
    float* latctx = ws + OFF_LATCTX;
    float* k2     = ws + OFF_K2;
    float* v2     = ws + OFF_V2;
    float* k2p    = ws + OFF_K2P;
    float* v2a    = ws + OFF_V2A;
    float* v2p    = ws + OFF_V2P;
    float* SB1    = ws + OFF_SB1;
    float* den    = ws + OFF_DEN;

    // zero the atomic-accumulate region (includes den)
    hipMemsetAsync(q1, 0, (WS_FLOATS - OFF_Q1) * sizeof(float), stream);

    k_stepb<<<dim3(P_), dim3(256), 0, stream>>>(qpos, plt, stepb);
    k_transpose<<<dim3(32,32,2), dim3(256), 0, stream>>>(w_ck, w_sq, ckwT, sqwT);

    // q1 = latents @ lat_q_w ; q1' = q1 @ ctx_k_w^T
    k_gemmT<8><<<dim3(1,4,8),  dim3(256), 0, stream>>>(lats, w_lq, q1,  8,  nullptr);
    k_gemmT<8><<<dim3(1,4,8),  dim3(256), 0, stream>>>(q1,   ckwT, q1p, 8,  nullptr);

    // SB1 = step_base @ gate_w1[:1024]  (independent of the attention pipeline)
    k_gemmT<8><<<dim3(90,4,8), dim3(256), 0, stream>>>(stepb, w_g1, SB1, P_, nullptr);

    // stage 1 attention over ctx: ONE pass (num + den fused)
    k_stage1<<<dim3(B_,16), dim3(256), 0, stream>>>(ctx, q1p, num, den);

    // lat_ctx chain; 1/den folded into the first GEMM's epilogue (row divide)
    k_gemmT<8><<<dim3(32,4,4), dim3(256), 0, stream>>>(num,  w_cv, tmp1,   256, den);
    k_gemmT<8><<<dim3(32,4,4), dim3(256), 0, stream>>>(tmp1, w_lo, latctx, 256, nullptr);
    // independent pairs fused into single launches
    k_gemm_pair<<<dim3(32,4,8), dim3(256), 0, stream>>>(latctx, w_lk, k2,
                                                        latctx, w_lv, v2, 256);
    k_gemm_pair<<<dim3(32,4,8), dim3(256), 0, stream>>>(k2, sqwT, k2p,
                                                        v2, w_so, v2a, 256);
    k_gemmT<8><<<dim3(32,4,4), dim3(256), 0, stream>>>(v2a, w_g1 + (size_t)D_*D_, v2p, 256, nullptr);

    // gating
    k_f1<<<dim3(12, B_),    dim3(64),  0, stream>>>(stepb, k2p, attw);
    k_f2<<<dim3(B_, 12, 4), dim3(64),  0, stream>>>(SB1, v2p, attw, b_g1, w_g2, logitp);
    k_f3<<<dim3(P_, B_),    dim3(256), 0, stream>>>(logitp, b_g2, qexp, out);
}

// Round 4
// 988.902 us; speedup vs baseline: 1.4350x; 1.1712x over previous
//
#include <hip/hip_runtime.h>
#include <hip/hip_bf16.h>
#include <math.h>

#define D_  1024
#define B_  32
#define T_  2048
#define L_  8
#define P_  720
#define E_  16
#define BP_ (B_*P_)   /* 23040 */

// ---- workspace layout (float offsets) ----
#define OFF_STEPB   ((size_t)0)        // [720][1024]
#define OFF_CKWT    ((size_t)737280)   // ctx_k_w^T  [1024][1024]
#define OFF_SQWT    ((size_t)1785856)  // step_q_w^T [1024][1024]
#define OFF_ATTW    ((size_t)3358720)  // [B][P][8] attn2 weights
#define OFF_LOGITP  ((size_t)3543040)  // [4][B*P][16] logit partials
// ---- memset (atomic-accumulate) region starts here ----
#define OFF_Q1      ((size_t)5017600)  // [8][1024]
#define OFF_Q1P     ((size_t)5025792)  // [8][1024]
#define OFF_NUM     ((size_t)5033984)  // [B][L][1024] softmax numerator
#define OFF_TMP1    ((size_t)5296128)  // [256][1024]
#define OFF_LATCTX  ((size_t)5558272)
#define OFF_K2      ((size_t)5820416)
#define OFF_V2      ((size_t)6082560)
#define OFF_K2P     ((size_t)6344704)
#define OFF_V2A     ((size_t)6606848)
#define OFF_V2P     ((size_t)6868992)
#define OFF_SB1     ((size_t)7131136)  // [720][1024]
#define OFF_DEN     ((size_t)7868416)  // [256] raw softmax denominators (atomic)
// ---- memset region ends here ----
#define WS_FLOATS   ((size_t)7868672)  // ~31.5 MB

__device__ __forceinline__ float gelu_exact(float x){
    return 0.5f * x * (1.0f + erff(x * 0.70710678118654752f));
}

// step_base[p][d] = query_pos[p][d] + pred_len_table[720][d]
__global__ void k_stepb(const float* __restrict__ qpos, const float* __restrict__ plt,
                        float* __restrict__ stepb){
    int p = blockIdx.x;
    int d = threadIdx.x * 4;
    float4 a = *(const float4*)(qpos + (size_t)p*D_ + d);
    float4 b = *(const float4*)(plt  + (size_t)P_*D_ + d);
    a.x += b.x; a.y += b.y; a.z += b.z; a.w += b.w;
    *(float4*)(stepb + (size_t)p*D_ + d) = a;
}

// transpose two 1024x1024 weights (z selects which)
__global__ void k_transpose(const float* __restrict__ s0, const float* __restrict__ s1,
                            float* __restrict__ d0, float* __restrict__ d1){
    __shared__ float tile[32][33];
    const float* src = blockIdx.z ? s1 : s0;
    float*       dst = blockIdx.z ? d1 : d0;
    int tx = threadIdx.x & 31, ty = threadIdx.x >> 5;
    int bx = blockIdx.x * 32, by = blockIdx.y * 32;
    #pragma unroll
    for (int r = 0; r < 4; r++)
        tile[ty + 8*r][tx] = src[(size_t)(by + ty + 8*r)*D_ + bx + tx];
    __syncthreads();
    #pragma unroll
    for (int r = 0; r < 4; r++)
        dst[(size_t)(bx + ty + 8*r)*D_ + by + tx] = tile[tx][ty + 8*r];
}

// C[M,1024] (+)= A[M,1024(chunk)] @ B[1024(chunk),1024] (/rowdiv); split-K via gridDim.z,
// atomic epilogue.
template<int MR>
__global__ void k_gemmT(const float* __restrict__ A, const float* __restrict__ B,
                        float* __restrict__ C, int M, const float* __restrict__ rowdiv){
    int n  = blockIdx.y * 256 + threadIdx.x;
    int kc = D_ / gridDim.z;
    int k0 = blockIdx.z * kc;
    int mb = blockIdx.x * MR;
    float acc[MR];
    #pragma unroll
    for (int m = 0; m < MR; m++) acc[m] = 0.f;
    for (int k = k0; k < k0 + kc; k += 4){
        float b0 = B[(size_t)(k+0)*D_ + n];
        float b1 = B[(size_t)(k+1)*D_ + n];
        float b2 = B[(size_t)(k+2)*D_ + n];
        float b3 = B[(size_t)(k+3)*D_ + n];
        #pragma unroll
        for (int m = 0; m < MR; m++){
            int row = mb + m; if (row > M - 1) row = M - 1;   // uniform clamp
            const float4 av = *(const float4*)(A + (size_t)row*D_ + k);
            acc[m] += av.x*b0 + av.y*b1 + av.z*b2 + av.w*b3;
        }
    }
    #pragma unroll
    for (int m = 0; m < MR; m++){
        int row = mb + m;
        if (row < M){
            float v = acc[m];
            if (rowdiv) v /= rowdiv[row];
            atomicAdd(C + (size_t)row*D_ + n, v);
        }
    }
}

// two independent GEMMs in one launch (blockIdx.z LSB selects), MR=8.
__global__ void k_gemm_pair(const float* __restrict__ A0, const float* __restrict__ B0, float* __restrict__ C0,
                            const float* __restrict__ A1, const float* __restrict__ B1, float* __restrict__ C1,
                            int M){
    const int which = blockIdx.z & 1;
    const float* A  = which ? A1 : A0;
    const float* Bm = which ? B1 : B0;
    float*       C  = which ? C1 : C0;
    int zn = gridDim.z >> 1;
    int z  = blockIdx.z >> 1;
    int n  = blockIdx.y * 256 + threadIdx.x;
    int kc = D_ / zn;
    int k0 = z * kc;
    int mb = blockIdx.x * 8;
    float acc[8];
    #pragma unroll
    for (int m = 0; m < 8; m++) acc[m] = 0.f;
    for (int k = k0; k < k0 + kc; k += 4){
        float b0 = Bm[(size_t)(k+0)*D_ + n];
        float b1 = Bm[(size_t)(k+1)*D_ + n];
        float b2 = Bm[(size_t)(k+2)*D_ + n];
        float b3 = Bm[(size_t)(k+3)*D_ + n];
        #pragma unroll
        for (int m = 0; m < 8; m++){
            int row = mb + m; if (row > M - 1) row = M - 1;
            const float4 av = *(const float4*)(A + (size_t)row*D_ + k);
            acc[m] += av.x*b0 + av.y*b1 + av.z*b2 + av.w*b3;
        }
    }
    #pragma unroll
    for (int m = 0; m < 8; m++){
        int row = mb + m;
        if (row < M){
            atomicAdd(C + (size_t)row*D_ + n, acc[m]);
        }
    }
}

// Fused stage-1 attention, v2: wave-autonomous register streaming (no ctx LDS, no
// per-tile barriers). Each of 4 waves streams 32 rows; lane owns a 16-float d-slice
// (d = c*256 + 4*lane + j). q1p pre-permuted into LDS q1pL[lane][l*16+c*4+j] with
// row stride 129 -> bank (lane+off)&31 -> 2-way (free). Per row-pair: 256 FMA dots,
// reduce-scatter (7 shfl) + 3 shfl group-sum -> lane holds dot for l=lane&7, exp,
// 8-shfl broadcast, 256 FMA accumulate. Epilogue: wave-sequential LDS merge, then
// one atomic set per block (same 4.2M total atomics as v1).
__global__ __launch_bounds__(256) void k_stage1(const float* __restrict__ ctx,
                                                const float* __restrict__ q1p,
                                                float* __restrict__ num,
                                                float* __restrict__ den){
    __shared__ float q1pL[64*129];     // 33,024 B
    __shared__ float accsh[8][1028];   // 32,896 B   (total ~66 KB -> 2 blocks/CU)
    const int tid  = threadIdx.x;
    const int lane = tid & 63;
    const int wav  = tid >> 6;
    const int b    = blockIdx.x;

    // ---- stage q1p into lane-permuted LDS (one-time) ----
    for (int idx = tid; idx < 2048; idx += 256){
        int ln = idx >> 5;          // 0..63
        int r  = idx & 31;          // 0..31
        int l  = r >> 2;            // 0..7
        int c  = r & 3;             // 0..3
        float4 v = *(const float4*)(q1p + (size_t)l*D_ + c*256 + ln*4);
        *(float4*)&q1pL[ln*129 + l*16 + c*4] = v;
    }
    __syncthreads();

    const int t0 = blockIdx.y*128 + wav*32;
    const float4* rp = (const float4*)(ctx + ((size_t)b*T_ + t0)*D_);

    float4 acc[8][4];
    #pragma unroll
    for (int l = 0; l < 8; l++)
        #pragma unroll
        for (int c = 0; c < 4; c++) acc[l][c] = make_float4(0.f,0.f,0.f,0.f);
    float denacc = 0.f;

    const int b0 = lane & 1, b1 = (lane>>1)&1, b2 = (lane>>2)&1;
    const float* qbase = &q1pL[lane*129];

    float4 cur0[4], cur1[4], nx0[4], nx1[4];
    #pragma unroll
    for (int c = 0; c < 4; c++){
        cur0[c] = rp[(size_t)0*256 + c*64 + lane];
        cur1[c] = rp[(size_t)1*256 + c*64 + lane];
    }

    for (int i = 0; i < 32; i += 2){
        if (i < 30){
            #pragma unroll
            for (int c = 0; c < 4; c++){
                nx0[c] = rp[(size_t)(i+2)*256 + c*64 + lane];
                nx1[c] = rp[(size_t)(i+3)*256 + c*64 + lane];
            }
        }
        // ---- dot partials over lane's 16-float slice, both rows ----
        float p0[8], p1[8];
        #pragma unroll
        for (int l = 0; l < 8; l++){
            float s0 = 0.f, s1 = 0.f;
            #pragma unroll
            for (int c = 0; c < 4; c++){
                float4 q = *(const float4*)(qbase + l*16 + c*4);
                s0 += cur0[c].x*q.x + cur0[c].y*q.y + cur0[c].z*q.z + cur0[c].w*q.w;
                s1 += cur1[c].x*q.x + cur1[c].y*q.y + cur1[c].z*q.z + cur1[c].w*q.w;
            }
            p0[l] = s0; p1[l] = s1;
        }
        // ---- reduce-scatter: lane ends with full dot for l = lane&7 ----
        float e0, e1;
        {
            float u0 = b0 ? p0[1] : p0[0], w0 = b0 ? p0[0] : p0[1];
            float u1 = b0 ? p0[3] : p0[2], w1 = b0 ? p0[2] : p0[3];
            float u2 = b0 ? p0[5] : p0[4], w2 = b0 ? p0[4] : p0[5];
            float u3 = b0 ? p0[7] : p0[6], w3 = b0 ? p0[6] : p0[7];
            u0 += __shfl_xor(w0,1); u1 += __shfl_xor(w1,1);
            u2 += __shfl_xor(w2,1); u3 += __shfl_xor(w3,1);
            float x0 = b1 ? u1 : u0, y0 = b1 ? u0 : u1;
            float x1 = b1 ? u3 : u2, y1 = b1 ? u2 : u3;
            x0 += __shfl_xor(y0,2); x1 += __shfl_xor(y1,2);
            float z = b2 ? x1 : x0, zz = b2 ? x0 : x1;
            z += __shfl_xor(zz,4);
            z += __shfl_xor(z,8); z += __shfl_xor(z,16); z += __shfl_xor(z,32);
            e0 = __expf(z * 0.03125f);
        }
        {
            float u0 = b0 ? p1[1] : p1[0], w0 = b0 ? p1[0] : p1[1];
            float u1 = b0 ? p1[3] : p1[2], w1 = b0 ? p1[2] : p1[3];
            float u2 = b0 ? p1[5] : p1[4], w2 = b0 ? p1[4] : p1[5];
            float u3 = b0 ? p1[7] : p1[6], w3 = b0 ? p1[6] : p1[7];
            u0 += __shfl_xor(w0,1); u1 += __shfl_xor(w1,1);
            u2 += __shfl_xor(w2,1); u3 += __shfl_xor(w3,1);
            float x0 = b1 ? u1 : u0, y0 = b1 ? u0 : u1;
            float x1 = b1 ? u3 : u2, y1 = b1 ? u2 : u3;
            x0 += __shfl_xor(y0,2); x1 += __shfl_xor(y1,2);
            float z = b2 ? x1 : x0, zz = b2 ? x0 : x1;
            z += __shfl_xor(zz,4);
            z += __shfl_xor(z,8); z += __shfl_xor(z,16); z += __shfl_xor(z,32);
            e1 = __expf(z * 0.03125f);
        }
        denacc += e0 + e1;
        // ---- broadcast e[l] to all lanes ----
        float ee0[8], ee1[8];
        #pragma unroll
        for (int l = 0; l < 8; l++){ ee0[l] = __shfl(e0, l); ee1[l] = __shfl(e1, l); }
        // ---- accumulate num partials in registers ----
        #pragma unroll
        for (int l = 0; l < 8; l++)
            #pragma unroll
            for (int c = 0; c < 4; c++){
                acc[l][c].x += ee0[l]*cur0[c].x + ee1[l]*cur1[c].x;
                acc[l][c].y += ee0[l]*cur0[c].y + ee1[l]*cur1[c].y;
                acc[l][c].z += ee0[l]*cur0[c].z + ee1[l]*cur1[c].z;
                acc[l][c].w += ee0[l]*cur0[c].w + ee1[l]*cur1[c].w;
            }
        if (i < 30){
            #pragma unroll
            for (int c = 0; c < 4; c++){ cur0[c] = nx0[c]; cur1[c] = nx1[c]; }
        }
    }

    // ---- den: lanes 0..7 hold per-l totals (replicated 8x across lanes) ----
    if (lane < 8) atomicAdd(den + b*8 + lane, denacc);

    // ---- merge 4 waves' acc into accsh (wave-sequential, no LDS atomics) ----
    for (int w = 0; w < 4; w++){
        if (wav == w){
            #pragma unroll
            for (int l = 0; l < 8; l++)
                #pragma unroll
                for (int c = 0; c < 4; c++){
                    float* s = &accsh[l][c*256 + 4*lane];
                    if (w == 0){
                        *(float4*)s = acc[l][c];
                    } else {
                        float4 o = *(float4*)s;
                        o.x += acc[l][c].x; o.y += acc[l][c].y;
                        o.z += acc[l][c].z; o.w += acc[l][c].w;
                        *(float4*)s = o;
                    }
                }
        }
        __syncthreads();
    }

    // ---- global epilogue: one atomic set per block ----
    #pragma unroll
    for (int j = 0; j < 8; j++){
        int idx = j*256 + tid;          // 0..2047
        int l  = idx >> 8, d4 = idx & 255;
        float4 v = *(float4*)&accsh[l][4*d4];
        float* np_ = num + ((size_t)(b*8 + l))*D_ + 4*d4;
        atomicAdd(np_+0, v.x); atomicAdd(np_+1, v.y);
        atomicAdd(np_+2, v.z); atomicAdd(np_+3, v.w);
    }
}

// attn2 logits + softmax over L=8, thread-per-p:  attw[b][p][l]
__global__ void k_f1(const float* __restrict__ stepb, const float* __restrict__ k2p,
                     float* __restrict__ attw){
    int b = blockIdx.y;
    int p = blockIdx.x * 64 + threadIdx.x;
    if (p >= P_) return;
    const float4* sp = (const float4*)(stepb + (size_t)p * D_);
    const float* kp = k2p + (size_t)b * 8 * D_;
    float acc[8] = {0,0,0,0,0,0,0,0};
    #pragma unroll 2
    for (int d4 = 0; d4 < 256; d4++){
        float4 s = sp[d4];
        #pragma unroll
        for (int l = 0; l < 8; l++){
            const float4 kv = *(const float4*)(kp + (size_t)l*D_ + 4*d4);  // uniform -> s_load
            acc[l] += s.x*kv.x + s.y*kv.y + s.z*kv.z + s.w*kv.w;
        }
    }
    float s8[8];
    #pragma unroll
    for (int l = 0; l < 8; l++) s8[l] = acc[l] * 0.03125f;
    float m = s8[0];
    #pragma unroll
    for (int l = 1; l < 8; l++) m = fmaxf(m, s8[l]);
    float e8[8]; float sum = 0.f;
    #pragma unroll
    for (int l = 0; l < 8; l++){ e8[l] = __expf(s8[l] - m); sum += e8[l]; }
    float inv = 1.0f / sum;
    float4 o0 = make_float4(e8[0]*inv, e8[1]*inv, e8[2]*inv, e8[3]*inv);
    float4 o1 = make_float4(e8[4]*inv, e8[5]*inv, e8[6]*inv, e8[7]*inv);
    size_t bp = (size_t)b * P_ + p;
    *(float4*)(attw + bp*8)     = o0;
    *(float4*)(attw + bp*8 + 4) = o1;
}

// pre->gelu->logit partials over a d-quarter. Thread-per-p; weights via uniform s_loads.
__global__ void k_f2(const float* __restrict__ SB1, const float* __restrict__ v2p,
                     const float* __restrict__ attw, const float* __restrict__ b1,
                     const float* __restrict__ w2, float* __restrict__ logitp){
    int b  = blockIdx.x;
    int p  = blockIdx.y * 64 + threadIdx.x;
    int dq = blockIdx.z;
    if (p >= P_) return;
    size_t bp = (size_t)b * P_ + p;
    float a[8];
    {
        float4 a0 = *(const float4*)(attw + bp*8);
        float4 a1 = *(const float4*)(attw + bp*8 + 4);
        a[0]=a0.x; a[1]=a0.y; a[2]=a0.z; a[3]=a0.w;
        a[4]=a1.x; a[5]=a1.y; a[6]=a1.z; a[7]=a1.w;
    }
    float acc16[16];
    #pragma unroll
    for (int e = 0; e < 16; e++) acc16[e] = 0.f;
    const float* sbp = SB1 + (size_t)p * D_;
    int dbase = dq * 256;
    for (int dd = 0; dd < 256; dd += 4){
        int d = dbase + dd;
        float4 pre = *(const float4*)(sbp + d);
        float4 bb  = *(const float4*)(b1 + d);               // uniform
        pre.x += bb.x; pre.y += bb.y; pre.z += bb.z; pre.w += bb.w;
        #pragma unroll
        for (int l = 0; l < 8; l++){
            const float4 vv = *(const float4*)(v2p + ((size_t)(b*8 + l))*D_ + d);  // uniform
            pre.x += a[l]*vv.x; pre.y += a[l]*vv.y; pre.z += a[l]*vv.z; pre.w += a[l]*vv.w;
        }
        float h[4];
        h[0] = gelu_exact(pre.x); h[1] = gelu_exact(pre.y);
        h[2] = gelu_exact(pre.z); h[3] = gelu_exact(pre.w);
        #pragma unroll
        for (int i = 0; i < 4; i++){
            const float* w2r = w2 + (size_t)(d + i) * E_;    // uniform
            #pragma unroll
            for (int e = 0; e < 16; e++) acc16[e] += h[i] * w2r[e];
        }
    }
    float* outp = logitp + ((size_t)dq * BP_ + bp) * 16;
    #pragma unroll
    for (int e = 0; e < 16; e += 4){
        float4 v = make_float4(acc16[e], acc16[e+1], acc16[e+2], acc16[e+3]);
        *(float4*)(outp + e) = v;
    }
}

// top-2 + masked softmax + expert combine
__global__ void k_f3(const float* __restrict__ logitp, const float* __restrict__ b2,
                     const float* __restrict__ qe, float* __restrict__ out){
    int p = blockIdx.x, b = blockIdx.y;
    size_t bp = (size_t)b * P_ + p;
    float lg[16];
    #pragma unroll
    for (int e = 0; e < 16; e++){
        lg[e] = logitp[((size_t)0*BP_ + bp)*16 + e]
              + logitp[((size_t)1*BP_ + bp)*16 + e]
              + logitp[((size_t)2*BP_ + bp)*16 + e]
              + logitp[((size_t)3*BP_ + bp)*16 + e]
              + b2[e];
    }
    int e1 = 0; float l1 = lg[0];
    #pragma unroll
    for (int e = 1; e < 16; e++) if (lg[e] > l1){ l1 = lg[e]; e1 = e; }   // ties -> lowest idx
    int e2 = 0; float l2 = -1e30f;
    #pragma unroll
    for (int e = 0; e < 16; e++) if (e != e1 && lg[e] > l2){ l2 = lg[e]; e2 = e; }
    float q  = __expf(l2 - l1);
    float w1 = 1.0f / (1.0f + q);
    float w2 = q / (1.0f + q);
    int d = threadIdx.x * 4;
    float4 x1 = *(const float4*)(qe + ((size_t)e1 * P_ + p)*D_ + d);
    float4 x2 = *(const float4*)(qe + ((size_t)e2 * P_ + p)*D_ + d);
    float4 o;
    o.x = w1*x1.x + w2*x2.x; o.y = w1*x1.y + w2*x2.y;
    o.z = w1*x1.z + w2*x2.z; o.w = w1*x1.w + w2*x2.w;
    *(float4*)(out + bp*D_ + d) = o;
}

extern "C" void kernel_launch(void* const* d_in, const int* in_sizes, int n_in,
                              void* d_out, int out_size, void* d_ws, size_t ws_size,
                              hipStream_t stream) {
    (void)in_sizes; (void)n_in; (void)out_size; (void)ws_size;
    const float* ctx  = (const float*)d_in[0];
    const float* qexp = (const float*)d_in[1];
    const float* qpos = (const float*)d_in[2];
    const float* plt  = (const float*)d_in[3];
    const float* lats = (const float*)d_in[4];
    const float* w_lq = (const float*)d_in[5];
    const float* w_ck = (const float*)d_in[6];
    const float* w_cv = (const float*)d_in[7];
    const float* w_lo = (const float*)d_in[8];
    const float* w_sq = (const float*)d_in[9];
    const float* w_lk = (const float*)d_in[10];
    const float* w_lv = (const float*)d_in[11];
    const float* w_so = (const float*)d_in[12];
    const float* w_g1 = (const float*)d_in[13];
    const float* b_g1 = (const float*)d_in[14];
    const float* w_g2 = (const float*)d_in[15];
    const float* b_g2 = (const float*)d_in[16];
    float* out = (float*)d_out;
    float* ws  = (float*)d_ws;

    float* stepb  = ws + OFF_STEPB;
    float* ckwT   = ws + OFF_CKWT;
    float* sqwT   = ws + OFF_SQWT;
    float* attw   = ws + OFF_ATTW;
    float* logitp = ws + OFF_LOGITP;
    float* q1     = ws + OFF_Q1;
    float* q1p    = ws + OFF_Q1P;
    float* num    = ws + OFF_NUM;
    float* tmp1   = ws + OFF_TMP1;
    float* latctx = ws + OFF_LATCTX;
    float* k2     = ws + OFF_K2;
    float* v2     = ws + OFF_V2;
    float* k2p    = ws + OFF_K2P;
    float* v2a    = ws + OFF_V2A;
    float* v2p    = ws + OFF_V2P;
    float* SB1    = ws + OFF_SB1;
    float* den    = ws + OFF_DEN;

    // zero the atomic-accumulate region (includes den)
    hipMemsetAsync(q1, 0, (WS_FLOATS - OFF_Q1) * sizeof(float), stream);

    k_stepb<<<dim3(P_), dim3(256), 0, stream>>>(qpos, plt, stepb);
    k_transpose<<<dim3(32,32,2), dim3(256), 0, stream>>>(w_ck, w_sq, ckwT, sqwT);

    // q1 = latents @ lat_q_w ; q1' = q1 @ ctx_k_w^T
    k_gemmT<8><<<dim3(1,4,8),  dim3(256), 0, stream>>>(lats, w_lq, q1,  8,  nullptr);
    k_gemmT<8><<<dim3(1,4,8),  dim3(256), 0, stream>>>(q1,   ckwT, q1p, 8,  nullptr);

    // SB1 = step_base @ gate_w1[:1024]  (independent of the attention pipeline)
    k_gemmT<8><<<dim3(90,4,8), dim3(256), 0, stream>>>(stepb, w_g1, SB1, P_, nullptr);

    // stage 1 attention over ctx: ONE pass (num + den fused), wave-autonomous
    k_stage1<<<dim3(B_,16), dim3(256), 0, stream>>>(ctx, q1p, num, den);

    // lat_ctx chain; 1/den folded into the first GEMM's epilogue (row divide)
    k_gemmT<8><<<dim3(32,4,4), dim3(256), 0, stream>>>(num,  w_cv, tmp1,   256, den);
    k_gemmT<8><<<dim3(32,4,4), dim3(256), 0, stream>>>(tmp1, w_lo, latctx, 256, nullptr);
    // independent pairs fused into single launches
    k_gemm_pair<<<dim3(32,4,8), dim3(256), 0, stream>>>(latctx, w_lk, k2,
                                                        latctx, w_lv, v2, 256);
    k_gemm_pair<<<dim3(32,4,8), dim3(256), 0, stream>>>(k2, sqwT, k2p,
                                                        v2, w_so, v2a, 256);
    k_gemmT<8><<<dim3(32,4,4), dim3(256), 0, stream>>>(v2a, w_g1 + (size_t)D_*D_, v2p, 256, nullptr);

    // gating
    k_f1<<<dim3(12, B_),    dim3(64),  0, stream>>>(stepb, k2p, attw);
    k_f2<<<dim3(B_, 12, 4), dim3(64),  0, stream>>>(SB1, v2p, attw, b_g1, w_g2, logitp);
    k_f3<<<dim3(P_, B_),    dim3(256), 0, stream>>>(logitp, b_g2, qexp, out);
}